// Round 2
// baseline (656.139 us; speedup 1.0000x reference)
//
#include <hip/hip_runtime.h>

#define BB   256
#define TT   2048
#define DIN  10
#define UU   64
#define DOUT 2
#define CHUNK 64
#define HISTP 67   // hist row stride (odd -> conflict-free column reads)

__global__ __launch_bounds__(64) void rnn_scan_kernel(
    const float* __restrict__ x,    // [B,T,DIN]
    const float* __restrict__ Wx,   // [DIN,U]
    const float* __restrict__ Wh,   // [U,U]
    const float* __restrict__ bias, // [U]
    const float* __restrict__ Wd,   // [U,DOUT]
    const float* __restrict__ bd,   // [DOUT]
    float* __restrict__ out)        // [B,T,DOUT]
{
    __shared__ __align__(16) float hsh[UU];        // current h (broadcast buffer)
    __shared__ float hist[CHUNK * HISTP];          // h history for output epilogue
    __shared__ __align__(16) float xs[CHUNK * 12]; // staged x rows, 12-float stride
    __shared__ __align__(8)  float wdl[UU * 2];    // Wd rows as (w0,w1) pairs

    const int l = threadIdx.x;   // 0..63
    const int b = blockIdx.x;    // sequence index
    const int g = l >> 4;        // k-quarter this lane sums
    const int r = l & 15;

    // ---- weights into registers ----
    // lane computes partials for units c(j) = r + 16*j over k in [16g, 16g+16)
    float w2x[4][8], w2y[4][8];
#pragma unroll
    for (int j = 0; j < 4; ++j) {
#pragma unroll
        for (int m = 0; m < 8; ++m) {
            const int k0 = g * 16 + 2 * m;
            const int c  = r + 16 * j;
            w2x[j][m] = Wh[(size_t)k0 * UU + c];
            w2y[j][m] = Wh[(size_t)(k0 + 1) * UU + c];
        }
    }
    float wx[DIN];
#pragma unroll
    for (int d = 0; d < DIN; ++d) wx[d] = Wx[d * UU + l];
    const float bl  = bias[l];
    const float bd0 = bd[0], bd1 = bd[1];

    // Wd to LDS
    wdl[2 * l + 0] = Wd[l * DOUT + 0];
    wdl[2 * l + 1] = Wd[l * DOUT + 1];
    hsh[l] = 0.0f;
    __syncthreads();

    float h = 0.0f;
    const float* xb = x + (size_t)b * TT * DIN;
    float*       ob = out + (size_t)b * TT * DOUT;

    for (int c = 0; c < TT / CHUNK; ++c) {
        // ---- stage x rows for this chunk: lane l loads row (c*64 + l), 10 floats ----
        {
            const float* xr = xb + (size_t)(c * CHUNK + l) * DIN;
            float2 v0 = *(const float2*)(xr + 0);
            float2 v1 = *(const float2*)(xr + 2);
            float2 v2 = *(const float2*)(xr + 4);
            float2 v3 = *(const float2*)(xr + 6);
            float2 v4 = *(const float2*)(xr + 8);
            float* dst = &xs[l * 12];
            ((float2*)dst)[0] = v0; ((float2*)dst)[1] = v1; ((float2*)dst)[2] = v2;
            ((float2*)dst)[3] = v3; ((float2*)dst)[4] = v4;
        }
        __syncthreads();

#pragma unroll 1
        for (int s = 0; s < CHUNK; ++s) {
            // read this lane's k-quarter of h (16 floats, 4x b128, 2-way aliasing = free)
            const float4* hq = (const float4*)&hsh[g * 16];
            float4 ha = hq[0], hb = hq[1], hc = hq[2], hd = hq[3];
            const float hv[16] = { ha.x, ha.y, ha.z, ha.w,  hb.x, hb.y, hb.z, hb.w,
                                   hc.x, hc.y, hc.z, hc.w,  hd.x, hd.y, hd.z, hd.w };

            float px[4] = {0.f, 0.f, 0.f, 0.f};
            float py[4] = {0.f, 0.f, 0.f, 0.f};
#pragma unroll
            for (int m = 0; m < 8; ++m) {
#pragma unroll
                for (int j = 0; j < 4; ++j) {
                    px[j] = fmaf(hv[2 * m],     w2x[j][m], px[j]);
                    py[j] = fmaf(hv[2 * m + 1], w2y[j][m], py[j]);
                }
            }
            float p0 = px[0] + py[0];
            float p1 = px[1] + py[1];
            float p2 = px[2] + py[2];
            float p3 = px[3] + py[3];

            // butterfly allreduce across the 4 k-quarters (lanes xor 16, xor 32)
            p0 += __shfl_xor(p0, 16); p0 += __shfl_xor(p0, 32);
            p1 += __shfl_xor(p1, 16); p1 += __shfl_xor(p1, 32);
            p2 += __shfl_xor(p2, 16); p2 += __shfl_xor(p2, 32);
            p3 += __shfl_xor(p3, 16); p3 += __shfl_xor(p3, 32);
            const float pg = (g & 2) ? ((g & 1) ? p3 : p2)
                                     : ((g & 1) ? p1 : p0);

            // xp_t[l] = b[l] + sum_d x[t][d] * Wx[d][l]   (x broadcast from LDS)
            const float* xr = &xs[s * 12];
            float z = bl + pg;
#pragma unroll
            for (int d = 0; d < DIN; ++d) z = fmaf(xr[d], wx[d], z);

            // tanh(z) = 1 - 2/(exp(2z)+1)  (saturates correctly at +-inf)
            const float e = __expf(2.0f * z);
            h = 1.0f - 2.0f * __builtin_amdgcn_rcpf(e + 1.0f);

            hsh[l] = h;
            hist[s * HISTP + l] = h;
            __syncthreads();
        }

        // ---- epilogue: lane l emits output for timestep c*64 + l ----
        {
            float a0 = bd0, a1 = bd1;
#pragma unroll
            for (int k = 0; k < UU; ++k) {
                const float hv = hist[l * HISTP + k];
                a0 = fmaf(hv, wdl[2 * k + 0], a0);
                a1 = fmaf(hv, wdl[2 * k + 1], a1);
            }
            float2 o; o.x = a0; o.y = a1;
            *(float2*)(ob + (size_t)(c * CHUNK + l) * DOUT) = o;
        }
        __syncthreads();  // protect xs/hist before next chunk overwrites
    }
}

extern "C" void kernel_launch(void* const* d_in, const int* in_sizes, int n_in,
                              void* d_out, int out_size, void* d_ws, size_t ws_size,
                              hipStream_t stream) {
    const float* x    = (const float*)d_in[0];
    const float* Wx   = (const float*)d_in[1];
    const float* Wh   = (const float*)d_in[2];
    const float* bias = (const float*)d_in[3];
    const float* Wd   = (const float*)d_in[4];
    const float* bd   = (const float*)d_in[5];
    float* out = (float*)d_out;

    rnn_scan_kernel<<<BB, 64, 0, stream>>>(x, Wx, Wh, bias, Wd, bd, out);
}

// Round 3
// 525.677 us; speedup vs baseline: 1.2482x; 1.2482x over previous
//
#include <hip/hip_runtime.h>

#define BB    256
#define TT    2048
#define DIN   10
#define UU    64
#define DOUT  2
#define CHUNK 64
#define HISTP 67   // odd stride -> conflict-free epilogue column reads

typedef float f32x2 __attribute__((ext_vector_type(2)));

// Broadcast h from lane ((l & 0x30) | M) to all lanes of its 16-lane row.
// ds_swizzle BitMode: src = ((self & and) | or) ^ xor ; imm = xor<<10 | or<<5 | and
template <int M>
__device__ __forceinline__ void bcast16(float h, float* hv) {
    hv[M] = __int_as_float(
        __builtin_amdgcn_ds_swizzle(__float_as_int(h), (M << 5) | 0x10));
    if constexpr (M < 15) bcast16<M + 1>(h, hv);
}

__global__ __launch_bounds__(64) void rnn_scan_kernel(
    const float* __restrict__ x,    // [B,T,DIN]
    const float* __restrict__ Wx,   // [DIN,U]
    const float* __restrict__ Wh,   // [U,U]
    const float* __restrict__ bias, // [U]
    const float* __restrict__ Wd,   // [U,DOUT]
    const float* __restrict__ bd,   // [DOUT]
    float* __restrict__ out)        // [B,T,DOUT]
{
    // Single wave per block: DS ops execute in program order per wave,
    // so NO __syncthreads() is needed anywhere in this kernel.
    __shared__ __align__(16) float xs[CHUNK * 12]; // staged x rows
    __shared__ float hist[CHUNK * HISTP];          // h history for epilogue
    __shared__ __align__(8)  float wdl[UU * 2];    // Wd rows (w0,w1)

    const int l = threadIdx.x;   // 0..63
    const int b = blockIdx.x;    // sequence
    const int g = l >> 4;        // k-quarter owned by this lane
    const int r = l & 15;
    const bool hiG = (l & 32) != 0;  // g in {2,3}
    const bool odG = (l & 16) != 0;  // g odd

    // ---- Wh fragments: lane (g,r) covers k in [16g,16g+16) for units c = r+16j.
    // Packed by k-pairs for v_pk_fma_f32.
    f32x2 w2[4][8];
#pragma unroll
    for (int j = 0; j < 4; ++j) {
        const int c = r + 16 * j;
#pragma unroll
        for (int m = 0; m < 8; ++m) {
            const int k0 = 16 * g + 2 * m;
            f32x2 w;
            w.x = Wh[(size_t)k0 * UU + c];
            w.y = Wh[(size_t)(k0 + 1) * UU + c];
            w2[j][m] = w;
        }
    }
    float wx[DIN];
#pragma unroll
    for (int d = 0; d < DIN; ++d) wx[d] = Wx[d * UU + l];
    const float bl  = bias[l];
    const float bd0 = bd[0], bd1 = bd[1];
    wdl[2 * l + 0] = Wd[l * DOUT + 0];
    wdl[2 * l + 1] = Wd[l * DOUT + 1];

    float h = 0.0f;
    const float* xb = x + (size_t)b * TT * DIN;
    float*       ob = out + (size_t)b * TT * DOUT;

    for (int c = 0; c < TT / CHUNK; ++c) {
        // ---- stage x rows for this chunk (coalesced; lane l loads row c*64+l)
        {
            const float* xr = xb + (size_t)(c * CHUNK + l) * DIN;
            float2 v0 = *(const float2*)(xr + 0);
            float2 v1 = *(const float2*)(xr + 2);
            float2 v2 = *(const float2*)(xr + 4);
            float2 v3 = *(const float2*)(xr + 6);
            float2 v4 = *(const float2*)(xr + 8);
            float* dst = &xs[l * 12];
            ((float2*)dst)[0] = v0; ((float2*)dst)[1] = v1; ((float2*)dst)[2] = v2;
            ((float2*)dst)[3] = v3; ((float2*)dst)[4] = v4;
        }
        // same-wave DS ordering makes xs visible to the step loop below

#pragma unroll 2
        for (int s = 0; s < CHUNK; ++s) {
            // 1) register broadcast of h within each 16-lane row (no LDS buffer)
            float hv[16];
            bcast16<0>(h, hv);

            // 2) xp for this lane's unit (independent of h -> fills swizzle latency)
            const float* xr = &xs[s * 12];
            float4 xa = *(const float4*)(xr + 0);
            float4 xb4 = *(const float4*)(xr + 4);
            float2 xc = *(const float2*)(xr + 8);
            float xp = bl;
            xp = fmaf(xa.x,  wx[0], xp); xp = fmaf(xa.y,  wx[1], xp);
            xp = fmaf(xa.z,  wx[2], xp); xp = fmaf(xa.w,  wx[3], xp);
            xp = fmaf(xb4.x, wx[4], xp); xp = fmaf(xb4.y, wx[5], xp);
            xp = fmaf(xb4.z, wx[6], xp); xp = fmaf(xb4.w, wx[7], xp);
            xp = fmaf(xc.x,  wx[8], xp); xp = fmaf(xc.y,  wx[9], xp);

            // 3) packed partial dots: 32 v_pk_fma_f32
            f32x2 acc0 = {0.f, 0.f}, acc1 = {0.f, 0.f},
                  acc2 = {0.f, 0.f}, acc3 = {0.f, 0.f};
#pragma unroll
            for (int m = 0; m < 8; ++m) {
                f32x2 h2; h2.x = hv[2 * m]; h2.y = hv[2 * m + 1];
                acc0 += h2 * w2[0][m];
                acc1 += h2 * w2[1][m];
                acc2 += h2 * w2[2][m];
                acc3 += h2 * w2[3][m];
            }
            float p0 = acc0.x + acc0.y;
            float p1 = acc1.x + acc1.y;
            float p2 = acc2.x + acc2.y;
            float p3 = acc3.x + acc3.y;

            // 4) reduce-scatter across the 4 k-quarters; z lands on its owner lane
            float s0 = hiG ? p0 : p2;
            float s1 = hiG ? p1 : p3;
            float r0 = __shfl_xor(s0, 32);
            float r1 = __shfl_xor(s1, 32);
            float a0 = (hiG ? p2 : p0) + r0;
            float a1 = (hiG ? p3 : p1) + r1;
            float s2 = odG ? a0 : a1;
            float r2 = __int_as_float(
                __builtin_amdgcn_ds_swizzle(__float_as_int(s2), 0x401F)); // xor 16
            float zr = (odG ? a1 : a0) + r2;

            // 5) activation
            float z = zr + xp;
            float e = __expf(2.0f * z);
            h = 1.0f - 2.0f * __builtin_amdgcn_rcpf(e + 1.0f);

            hist[s * HISTP + l] = h;   // off the critical path
        }

        // ---- epilogue: lane l emits output for timestep c*64 + l
        {
            float a0 = bd0, a1 = bd1;
#pragma unroll
            for (int k = 0; k < UU; ++k) {
                const float hvv = hist[l * HISTP + k];
                a0 = fmaf(hvv, wdl[2 * k + 0], a0);
                a1 = fmaf(hvv, wdl[2 * k + 1], a1);
            }
            float2 o; o.x = a0; o.y = a1;
            *(float2*)(ob + (size_t)(c * CHUNK + l) * DOUT) = o;
        }
    }
}

extern "C" void kernel_launch(void* const* d_in, const int* in_sizes, int n_in,
                              void* d_out, int out_size, void* d_ws, size_t ws_size,
                              hipStream_t stream) {
    const float* x    = (const float*)d_in[0];
    const float* Wx   = (const float*)d_in[1];
    const float* Wh   = (const float*)d_in[2];
    const float* bias = (const float*)d_in[3];
    const float* Wd   = (const float*)d_in[4];
    const float* bd   = (const float*)d_in[5];
    float* out = (float*)d_out;

    rnn_scan_kernel<<<BB, 64, 0, stream>>>(x, Wx, Wh, bias, Wd, bd, out);
}

// Round 4
// 391.399 us; speedup vs baseline: 1.6764x; 1.3431x over previous
//
#include <hip/hip_runtime.h>

#define BB    256
#define TT    2048
#define DIN   10
#define UU    64
#define DOUT  2
#define CHUNK 64
#define HISTP 67   // odd stride -> conflict-free epilogue column reads

typedef float f32x2 __attribute__((ext_vector_type(2)));

#if __has_builtin(__builtin_amdgcn_permlane32_swap)
#define HAS_PL32 1
#else
#define HAS_PL32 0
#endif
#if __has_builtin(__builtin_amdgcn_permlane16_swap)
#define HAS_PL16 1
#else
#define HAS_PL16 0
#endif

template <int N> struct IC { static constexpr int value = N; };

#if HAS_PL32
__device__ __forceinline__ float swapadd32(float a, float b) {
    auto t = __builtin_amdgcn_permlane32_swap(__float_as_uint(a), __float_as_uint(b), false, false);
    return __uint_as_float(t[0]) + __uint_as_float(t[1]);
}
__device__ __forceinline__ float pl32_first(float v) {
    auto t = __builtin_amdgcn_permlane32_swap(__float_as_uint(v), __float_as_uint(v), false, false);
    return __uint_as_float(t[0]);
}
#endif
#if HAS_PL16
__device__ __forceinline__ float swapadd16(float a, float b) {
    auto t = __builtin_amdgcn_permlane16_swap(__float_as_uint(a), __float_as_uint(b), false, false);
    return __uint_as_float(t[0]) + __uint_as_float(t[1]);
}
__device__ __forceinline__ float pl16_first(float v) {
    auto t = __builtin_amdgcn_permlane16_swap(__float_as_uint(v), __float_as_uint(v), false, false);
    return __uint_as_float(t[0]);
}
#endif

__device__ __forceinline__ float swz_xor16(float v) {
    return __int_as_float(__builtin_amdgcn_ds_swizzle(__float_as_int(v), 0x401F));
}

// 15 independent DPP row-rotations: hr[J] = h from lane (l & 0x30) | ((r + J*dstep) & 15)
template <int J>
__device__ __forceinline__ void ror_fill(int hb, float* hr) {
    hr[J] = __int_as_float(__builtin_amdgcn_mov_dpp(hb, 0x120 + J, 0xF, 0xF, false));
    if constexpr (J < 15) ror_fill<J + 1>(hb, hr);
}

// Reduce-scatter across the 4 k-quarters. MODE 0: all-VALU permlane network.
// MODE 1: permlane32 + ds_swizzle xor16. MODE 2: shfl + swizzle (round-3 path).
template <int MODE>
__device__ __forceinline__ float reduce4(float p0, float p1, float p2, float p3, int l) {
#if HAS_PL32
    if constexpr (MODE <= 1) {
        float u02 = swapadd32(p0, p2);
        float u13 = swapadd32(p1, p3);
#if HAS_PL16
        if constexpr (MODE == 0) {
            return swapadd16(u02, u13);
        }
#endif
        {
            bool od = (l & 16) != 0;
            float send = od ? u02 : u13;
            float recv = swz_xor16(send);
            return (od ? u13 : u02) + recv;
        }
    }
#endif
    {
        bool hi = (l & 32) != 0, od = (l & 16) != 0;
        float s0 = hi ? p0 : p2, s1 = hi ? p1 : p3;
        float r0 = __shfl_xor(s0, 32), r1 = __shfl_xor(s1, 32);
        float a0 = (hi ? p2 : p0) + r0;
        float a1 = (hi ? p3 : p1) + r1;
        float s2 = od ? a0 : a1;
        float r2 = swz_xor16(s2);
        return (od ? a1 : a0) + r2;
    }
}

__global__ __launch_bounds__(64) void rnn_scan_kernel(
    const float* __restrict__ x,    // [B,T,DIN]
    const float* __restrict__ Wx,   // [DIN,U]
    const float* __restrict__ Wh,   // [U,U]
    const float* __restrict__ bias, // [U]
    const float* __restrict__ Wd,   // [U,DOUT]
    const float* __restrict__ bd,   // [DOUT]
    float* __restrict__ out)        // [B,T,DOUT]
{
    // Single wave per block: per-wave DS/program ordering, no __syncthreads needed.
    __shared__ __align__(16) float xs[CHUNK * 12];
    __shared__ float hist[CHUNK * HISTP];
    __shared__ __align__(8)  float wdl[UU * 2];

    const int l = threadIdx.x;
    const int b = blockIdx.x;
    const int g = l >> 4;
    const int r = l & 15;

    // --- probe DPP row_ror direction (init-only, direction-proof) ---
    int dstep;
    {
        int q = __builtin_amdgcn_mov_dpp(r, 0x121, 0xF, 0xF, false); // ror:1 on r
        dstep = (q - r) & 15;  // +1 or 15 (== -1)
    }

    // --- probe permlane swap semantics; choose reduce mode + relabel bits ---
    int mode = 2, alt32 = 0, alt16 = 0;
#if HAS_PL32
    {
        float A = pl32_first((l & 32) ? 2.0f : 1.0f);
        int m0 = __all(A == 1.0f), m1 = __all(A == 2.0f);
        if (m0 | m1) { mode = 1; alt32 = m1 ? 1 : 0; }
    }
#if HAS_PL16
    if (mode == 1) {
        float A = pl16_first((float)g);
        int m0 = __all(A == (float)(g & ~1)), m1 = __all(A == (float)(g | 1));
        if (m0 | m1) { mode = 0; alt16 = m1 ? 1 : 0; }
    }
#endif
#endif
    if (mode == 2) alt32 = 0;
    if (mode != 0) alt16 = 0;

    // --- Wh fragments: slot j's unit column is chosen so the fixed reduce
    //     network lands unit l's sum on lane l under the probed semantics.
    f32x2 w2[4][8];
#pragma unroll
    for (int j = 0; j < 4; ++j) {
        const int rho = ((j & 1) ^ alt16) | (((((j >> 1) & 1) ^ alt32) & 1) << 1);
        const int cj = r + 16 * rho;
#pragma unroll
        for (int m = 0; m < 8; ++m) {
            const int k0 = 16 * g + ((r + (2 * m) * dstep) & 15);
            const int k1 = 16 * g + ((r + (2 * m + 1) * dstep) & 15);
            f32x2 w;
            w.x = Wh[(size_t)k0 * UU + cj];
            w.y = Wh[(size_t)k1 * UU + cj];
            w2[j][m] = w;
        }
    }

    float wx[DIN];
#pragma unroll
    for (int d = 0; d < DIN; ++d) wx[d] = Wx[d * UU + l];
    const float bl  = bias[l];
    const float bd0 = bd[0], bd1 = bd[1];
    wdl[2 * l + 0] = Wd[l * DOUT + 0];
    wdl[2 * l + 1] = Wd[l * DOUT + 1];

    const float* xb = x + (size_t)b * TT * DIN;
    float*       ob = out + (size_t)b * TT * DOUT;

    auto body = [&](auto MC) {
        constexpr int MODE = decltype(MC)::value;
        float h = 0.0f;
        for (int c = 0; c < TT / CHUNK; ++c) {
            // stage x rows for this chunk (coalesced)
            {
                const float* xr = xb + (size_t)(c * CHUNK + l) * DIN;
                float2 v0 = *(const float2*)(xr + 0);
                float2 v1 = *(const float2*)(xr + 2);
                float2 v2 = *(const float2*)(xr + 4);
                float2 v3 = *(const float2*)(xr + 6);
                float2 v4 = *(const float2*)(xr + 8);
                float* dst = &xs[l * 12];
                ((float2*)dst)[0] = v0; ((float2*)dst)[1] = v1; ((float2*)dst)[2] = v2;
                ((float2*)dst)[3] = v3; ((float2*)dst)[4] = v4;
            }

#pragma unroll 2
            for (int s = 0; s < CHUNK; ++s) {
                // 1) broadcast h within each 16-lane row: 15 independent DPP rotations
                float hr[16];
                hr[0] = h;
                ror_fill<1>(__float_as_int(h), hr);
                f32x2 hp[8];
#pragma unroll
                for (int m = 0; m < 8; ++m) {
                    f32x2 t; t.x = hr[2 * m]; t.y = hr[2 * m + 1]; hp[m] = t;
                }

                // 2) xp (independent of h -> overlaps DPP/FMA latency)
                const float* xr = &xs[s * 12];
                float4 xa  = *(const float4*)(xr + 0);
                float4 xbv = *(const float4*)(xr + 4);
                float2 xc  = *(const float2*)(xr + 8);
                float xp = bl;
                xp = fmaf(xa.x,  wx[0], xp); xp = fmaf(xa.y,  wx[1], xp);
                xp = fmaf(xa.z,  wx[2], xp); xp = fmaf(xa.w,  wx[3], xp);
                xp = fmaf(xbv.x, wx[4], xp); xp = fmaf(xbv.y, wx[5], xp);
                xp = fmaf(xbv.z, wx[6], xp); xp = fmaf(xbv.w, wx[7], xp);
                xp = fmaf(xc.x,  wx[8], xp); xp = fmaf(xc.y,  wx[9], xp);

                // 3) packed partial dots (32 v_pk_fma_f32)
                f32x2 a0 = {0.f, 0.f}, a1 = {0.f, 0.f}, a2 = {0.f, 0.f}, a3 = {0.f, 0.f};
#pragma unroll
                for (int m = 0; m < 8; ++m) {
                    a0 += hp[m] * w2[0][m];
                    a1 += hp[m] * w2[1][m];
                    a2 += hp[m] * w2[2][m];
                    a3 += hp[m] * w2[3][m];
                }

                // 4) all-VALU reduce-scatter; z lands on its owner lane
                float zr = reduce4<MODE>(a0.x + a0.y, a1.x + a1.y,
                                         a2.x + a2.y, a3.x + a3.y, l);

                // 5) activation: tanh(z) = 1 - 2/(exp(2z)+1)
                float z = zr + xp;
                float e = __expf(2.0f * z);
                h = 1.0f - 2.0f * __builtin_amdgcn_rcpf(e + 1.0f);

                hist[s * HISTP + l] = h;   // off the critical path
            }

            // epilogue: lane l emits output for timestep c*64 + l
            {
                float o0 = bd0, o1 = bd1;
#pragma unroll
                for (int k = 0; k < UU; ++k) {
                    const float hvv = hist[l * HISTP + k];
                    o0 = fmaf(hvv, wdl[2 * k + 0], o0);
                    o1 = fmaf(hvv, wdl[2 * k + 1], o1);
                }
                float2 o; o.x = o0; o.y = o1;
                *(float2*)(ob + (size_t)(c * CHUNK + l) * DOUT) = o;
            }
        }
    };

    if (mode == 0)      body(IC<0>{});
    else if (mode == 1) body(IC<1>{});
    else                body(IC<2>{});
}

extern "C" void kernel_launch(void* const* d_in, const int* in_sizes, int n_in,
                              void* d_out, int out_size, void* d_ws, size_t ws_size,
                              hipStream_t stream) {
    const float* x    = (const float*)d_in[0];
    const float* Wx   = (const float*)d_in[1];
    const float* Wh   = (const float*)d_in[2];
    const float* bias = (const float*)d_in[3];
    const float* Wd   = (const float*)d_in[4];
    const float* bd   = (const float*)d_in[5];
    float* out = (float*)d_out;

    rnn_scan_kernel<<<BB, 64, 0, stream>>>(x, Wx, Wh, bias, Wd, bd, out);
}

// Round 5
// 385.938 us; speedup vs baseline: 1.7001x; 1.0141x over previous
//
#include <hip/hip_runtime.h>

#define BB     256
#define TT     2048
#define DIN    10
#define UU     64
#define DOUT   2
#define CHUNK  64
#define NCHUNK (TT / CHUNK)
#define HISTP  67   // odd stride -> conflict-free epilogue column reads

typedef float f32x2 __attribute__((ext_vector_type(2)));
typedef float f32x4 __attribute__((ext_vector_type(4)));

#if __has_builtin(__builtin_elementwise_fma)
__device__ __forceinline__ f32x2 pkfma(f32x2 a, f32x2 b, f32x2 c) {
    return __builtin_elementwise_fma(a, b, c);
}
#else
__device__ __forceinline__ f32x2 pkfma(f32x2 a, f32x2 b, f32x2 c) {
    f32x2 r; r.x = fmaf(a.x, b.x, c.x); r.y = fmaf(a.y, b.y, c.y); return r;
}
#endif

#if __has_builtin(__builtin_amdgcn_permlane32_swap)
#define HAS_PL32 1
#else
#define HAS_PL32 0
#endif
#if __has_builtin(__builtin_amdgcn_permlane16_swap)
#define HAS_PL16 1
#else
#define HAS_PL16 0
#endif

template <int N> struct IC { static constexpr int value = N; };

#if HAS_PL32
__device__ __forceinline__ float swapadd32(float a, float b) {
    auto t = __builtin_amdgcn_permlane32_swap(__float_as_uint(a), __float_as_uint(b), false, false);
    return __uint_as_float(t[0]) + __uint_as_float(t[1]);
}
__device__ __forceinline__ float pl32_first(float v) {
    auto t = __builtin_amdgcn_permlane32_swap(__float_as_uint(v), __float_as_uint(v), false, false);
    return __uint_as_float(t[0]);
}
#endif
#if HAS_PL16
__device__ __forceinline__ float swapadd16(float a, float b) {
    auto t = __builtin_amdgcn_permlane16_swap(__float_as_uint(a), __float_as_uint(b), false, false);
    return __uint_as_float(t[0]) + __uint_as_float(t[1]);
}
__device__ __forceinline__ float pl16_first(float v) {
    auto t = __builtin_amdgcn_permlane16_swap(__float_as_uint(v), __float_as_uint(v), false, false);
    return __uint_as_float(t[0]);
}
#endif

__device__ __forceinline__ float swz_xor16(float v) {
    return __int_as_float(__builtin_amdgcn_ds_swizzle(__float_as_int(v), 0x401F));
}

// 15 DPP row-rotations writing DIRECTLY into the packed pk_fma operands:
// hp[J/2].{x,y} = h from lane (l & 0x30) | ((r + J*dstep) & 15)
template <int J>
__device__ __forceinline__ void ror_fill(int hb, f32x2* hp) {
    float v = __int_as_float(__builtin_amdgcn_mov_dpp(hb, 0x120 + J, 0xF, 0xF, false));
    if constexpr ((J & 1) == 0) hp[J / 2].x = v; else hp[J / 2].y = v;
    if constexpr (J < 15) ror_fill<J + 1>(hb, hp);
}

// Reduce-scatter across the 4 k-quarters.
// MODE 0: all-VALU permlane network. MODE 2: shfl + ds_swizzle fallback.
template <int MODE>
__device__ __forceinline__ float reduce4(float p0, float p1, float p2, float p3, int l) {
#if HAS_PL32 && HAS_PL16
    if constexpr (MODE == 0) {
        float u02 = swapadd32(p0, p2);
        float u13 = swapadd32(p1, p3);
        return swapadd16(u02, u13);
    }
#endif
    {
        bool hi = (l & 32) != 0, od = (l & 16) != 0;
        float s0 = hi ? p0 : p2, s1 = hi ? p1 : p3;
        float r0 = __shfl_xor(s0, 32), r1 = __shfl_xor(s1, 32);
        float a0 = (hi ? p2 : p0) + r0;
        float a1 = (hi ? p3 : p1) + r1;
        float s2 = od ? a0 : a1;
        float r2 = swz_xor16(s2);
        return (od ? a1 : a0) + r2;
    }
}

__global__ __launch_bounds__(64) void rnn_scan_kernel(
    const float* __restrict__ x,    // [B,T,DIN]
    const float* __restrict__ Wx,   // [DIN,U]
    const float* __restrict__ Wh,   // [U,U]
    const float* __restrict__ bias, // [U]
    const float* __restrict__ Wd,   // [U,DOUT]
    const float* __restrict__ bd,   // [DOUT]
    float* __restrict__ out)        // [B,T,DOUT]
{
    // Single wave per block: per-wave DS ordering, no __syncthreads needed.
    __shared__ __align__(16) float xs[CHUNK * 12];
    __shared__ float hist[CHUNK * HISTP];
    __shared__ __align__(8)  float wdl[UU * 2];

    const int l = threadIdx.x;
    const int b = blockIdx.x;
    const int g = l >> 4;
    const int r = l & 15;

    // --- probe DPP row_ror direction (init-only, direction-proof) ---
    int dstep;
    {
        int q = __builtin_amdgcn_mov_dpp(r, 0x121, 0xF, 0xF, false); // ror:1 on r
        dstep = (q - r) & 15;
    }

    // --- probe permlane swap semantics; pick reduce mode + relabel bits ---
    int mode = 2, alt32 = 0, alt16 = 0;
#if HAS_PL32 && HAS_PL16
    {
        float A = pl32_first((l & 32) ? 2.0f : 1.0f);
        int m0 = __all(A == 1.0f), m1 = __all(A == 2.0f);
        if (m0 | m1) {
            float Bv = pl16_first((float)g);
            int n0 = __all(Bv == (float)(g & ~1)), n1 = __all(Bv == (float)(g | 1));
            if (n0 | n1) { mode = 0; alt32 = m1 ? 1 : 0; alt16 = n1 ? 1 : 0; }
        }
    }
#endif
    if (mode != 0) { alt32 = 0; alt16 = 0; }

    // --- Wh fragments: slot j's unit column chosen so the fixed reduce
    //     network lands unit l's sum on lane l under the probed semantics.
    f32x2 w2[4][8];
#pragma unroll
    for (int j = 0; j < 4; ++j) {
        const int rho = ((j & 1) ^ alt16) | ((((j >> 1) & 1) ^ alt32) << 1);
        const int cj = r + 16 * rho;
#pragma unroll
        for (int m = 0; m < 8; ++m) {
            const int k0 = 16 * g + ((r + (2 * m) * dstep) & 15);
            const int k1 = 16 * g + ((r + (2 * m + 1) * dstep) & 15);
            f32x2 w;
            w.x = Wh[(size_t)k0 * UU + cj];
            w.y = Wh[(size_t)k1 * UU + cj];
            w2[j][m] = w;
        }
    }

    // Wx pairs for packed xp
    f32x2 wxp[5];
#pragma unroll
    for (int d2 = 0; d2 < 5; ++d2) {
        f32x2 w;
        w.x = Wx[(2 * d2) * UU + l];
        w.y = Wx[(2 * d2 + 1) * UU + l];
        wxp[d2] = w;
    }
    const float bl  = bias[l];
    const float bd0 = bd[0], bd1 = bd[1];
    wdl[2 * l + 0] = Wd[l * DOUT + 0];
    wdl[2 * l + 1] = Wd[l * DOUT + 1];

    const float* xb = x + (size_t)b * TT * DIN;
    float*       ob = out + (size_t)b * TT * DOUT;

    // prologue: prefetch chunk 0's x row for this lane into regs
    f32x2 xv[5];
    {
        const f32x2* xr = (const f32x2*)(xb + (size_t)l * DIN);
#pragma unroll
        for (int i = 0; i < 5; ++i) xv[i] = xr[i];
    }

    auto body = [&](auto MC) {
        constexpr int MODE = decltype(MC)::value;
        float h = 0.0f;
        for (int c = 0; c < NCHUNK; ++c) {
            // stage current chunk x (from regs) into LDS
            {
                f32x2* dst = (f32x2*)&xs[l * 12];
#pragma unroll
                for (int i = 0; i < 5; ++i) dst[i] = xv[i];
            }
            // async prefetch of next chunk into regs (lands during s-loop)
            if (c + 1 < NCHUNK) {
                const f32x2* xr = (const f32x2*)(xb + (size_t)((c + 1) * CHUNK + l) * DIN);
#pragma unroll
                for (int i = 0; i < 5; ++i) xv[i] = xr[i];
            }

#pragma unroll 4
            for (int s = 0; s < CHUNK; ++s) {
                // 1) broadcast h within each 16-lane row, direct to pk pairs
                f32x2 hp[8];
                hp[0].x = h;
                ror_fill<1>(__float_as_int(h), hp);

                // 2) packed xp (independent of h -> overlaps DPP latency)
                const float* xr = &xs[s * 12];
                f32x4 xa = ((const f32x4*)xr)[0];
                f32x4 xc = ((const f32x4*)xr)[1];
                f32x2 xe = ((const f32x2*)xr)[4];
                f32x2 xacc = {bl, 0.0f};
                xacc = pkfma(__builtin_shufflevector(xa, xa, 0, 1), wxp[0], xacc);
                xacc = pkfma(__builtin_shufflevector(xa, xa, 2, 3), wxp[1], xacc);
                xacc = pkfma(__builtin_shufflevector(xc, xc, 0, 1), wxp[2], xacc);
                xacc = pkfma(__builtin_shufflevector(xc, xc, 2, 3), wxp[3], xacc);
                xacc = pkfma(xe, wxp[4], xacc);
                float xp = xacc.x + xacc.y;

                // 3) packed partial dots: 32 v_pk_fma_f32
                f32x2 a0 = {0.f, 0.f}, a1 = {0.f, 0.f}, a2 = {0.f, 0.f}, a3 = {0.f, 0.f};
#pragma unroll
                for (int m = 0; m < 8; ++m) {
                    a0 = pkfma(hp[m], w2[0][m], a0);
                    a1 = pkfma(hp[m], w2[1][m], a1);
                    a2 = pkfma(hp[m], w2[2][m], a2);
                    a3 = pkfma(hp[m], w2[3][m], a3);
                }

                // 4) all-VALU reduce-scatter; z lands on its owner lane
                float zr = reduce4<MODE>(a0.x + a0.y, a1.x + a1.y,
                                         a2.x + a2.y, a3.x + a3.y, l);

                // 5) tanh(z) = 1 - 2/(exp2(2*log2e*z)+1)
                float z = zr + xp;
#if __has_builtin(__builtin_amdgcn_exp2f)
                float e = __builtin_amdgcn_exp2f(z * 2.8853900817779268f);
#else
                float e = __expf(2.0f * z);
#endif
                h = fmaf(-2.0f, __builtin_amdgcn_rcpf(e + 1.0f), 1.0f);

                hist[s * HISTP + l] = h;   // off the critical path
            }

            // epilogue: lane l emits output for timestep c*64 + l
            {
                float o0 = bd0, o1 = bd1;
#pragma unroll
                for (int k = 0; k < UU; ++k) {
                    const float hvv = hist[l * HISTP + k];
                    o0 = fmaf(hvv, wdl[2 * k + 0], o0);
                    o1 = fmaf(hvv, wdl[2 * k + 1], o1);
                }
                float2 o; o.x = o0; o.y = o1;
                *(float2*)(ob + (size_t)(c * CHUNK + l) * DOUT) = o;
            }
        }
    };

    if (mode == 0) body(IC<0>{});
    else           body(IC<2>{});
}

extern "C" void kernel_launch(void* const* d_in, const int* in_sizes, int n_in,
                              void* d_out, int out_size, void* d_ws, size_t ws_size,
                              hipStream_t stream) {
    const float* x    = (const float*)d_in[0];
    const float* Wx   = (const float*)d_in[1];
    const float* Wh   = (const float*)d_in[2];
    const float* bias = (const float*)d_in[3];
    const float* Wd   = (const float*)d_in[4];
    const float* bd   = (const float*)d_in[5];
    float* out = (float*)d_out;

    rnn_scan_kernel<<<BB, 64, 0, stream>>>(x, Wx, Wh, bias, Wd, bd, out);
}

// Round 6
// 304.061 us; speedup vs baseline: 2.1579x; 1.2693x over previous
//
#include <hip/hip_runtime.h>

#define BB     256
#define TT     2048
#define DIN    10
#define UU     64
#define DOUT   2
#define CHUNK  64
#define NCHUNK (TT / CHUNK)
#define HISTP  67   // odd stride -> conflict-free column reads

typedef float f32x2 __attribute__((ext_vector_type(2)));
typedef float f32x4 __attribute__((ext_vector_type(4)));

// 2*log2(e): recurrence is tracked as u = 1/(exp2(C*z)+1), h = 1-2u = tanh(z)
#define CSCALE 2.8853900817779268f

#if __has_builtin(__builtin_elementwise_fma)
__device__ __forceinline__ f32x2 pkfma(f32x2 a, f32x2 b, f32x2 c) {
    return __builtin_elementwise_fma(a, b, c);
}
#else
__device__ __forceinline__ f32x2 pkfma(f32x2 a, f32x2 b, f32x2 c) {
    f32x2 r; r.x = fmaf(a.x, b.x, c.x); r.y = fmaf(a.y, b.y, c.y); return r;
}
#endif

#if __has_builtin(__builtin_amdgcn_permlane32_swap) && __has_builtin(__builtin_amdgcn_permlane16_swap)
#define HAS_PL 1
#else
#define HAS_PL 0
#endif

template <int N> struct IC { static constexpr int value = N; };

#if HAS_PL
__device__ __forceinline__ float swapadd32(float a, float b) {
    auto t = __builtin_amdgcn_permlane32_swap(__float_as_uint(a), __float_as_uint(b), false, false);
    return __uint_as_float(t[0]) + __uint_as_float(t[1]);
}
__device__ __forceinline__ float pl32_first(float v) {
    auto t = __builtin_amdgcn_permlane32_swap(__float_as_uint(v), __float_as_uint(v), false, false);
    return __uint_as_float(t[0]);
}
__device__ __forceinline__ float swapadd16(float a, float b) {
    auto t = __builtin_amdgcn_permlane16_swap(__float_as_uint(a), __float_as_uint(b), false, false);
    return __uint_as_float(t[0]) + __uint_as_float(t[1]);
}
__device__ __forceinline__ float pl16_first(float v) {
    auto t = __builtin_amdgcn_permlane16_swap(__float_as_uint(v), __float_as_uint(v), false, false);
    return __uint_as_float(t[0]);
}
#endif

__device__ __forceinline__ float swz_xor16(float v) {
    return __int_as_float(__builtin_amdgcn_ds_swizzle(__float_as_int(v), 0x401F));
}

// 15 DPP row-rotations writing directly into packed pk_fma operand pairs:
// hp[J/2].{x,y} = u from lane (l & 0x30) | ((r + J*dstep) & 15)
template <int J>
__device__ __forceinline__ void ror_fill(int hb, f32x2* hp) {
    float v = __int_as_float(__builtin_amdgcn_mov_dpp(hb, 0x120 + J, 0xF, 0xF, false));
    if constexpr ((J & 1) == 0) hp[J / 2].x = v; else hp[J / 2].y = v;
    if constexpr (J < 15) ror_fill<J + 1>(hb, hp);
}

// Reduce-scatter across the 4 k-quarters. MODE 0: all-VALU permlane network.
// MODE 2: shfl + ds_swizzle fallback (proven in R3).
template <int MODE>
__device__ __forceinline__ float reduce4(float p0, float p1, float p2, float p3, int l) {
#if HAS_PL
    if constexpr (MODE == 0) {
        float u02 = swapadd32(p0, p2);
        float u13 = swapadd32(p1, p3);
        return swapadd16(u02, u13);
    }
#endif
    {
        bool hi = (l & 32) != 0, od = (l & 16) != 0;
        float s0 = hi ? p0 : p2, s1 = hi ? p1 : p3;
        float r0 = __shfl_xor(s0, 32), r1 = __shfl_xor(s1, 32);
        float a0 = (hi ? p2 : p0) + r0;
        float a1 = (hi ? p3 : p1) + r1;
        float s2 = od ? a0 : a1;
        float r2 = swz_xor16(s2);
        return (od ? a1 : a0) + r2;
    }
}

__global__ __launch_bounds__(128) void rnn_scan_kernel(
    const float* __restrict__ x,    // [B,T,DIN]
    const float* __restrict__ Wx,   // [DIN,U]
    const float* __restrict__ Wh,   // [U,U]
    const float* __restrict__ bias, // [U]
    const float* __restrict__ Wd,   // [U,DOUT]
    const float* __restrict__ bd,   // [DOUT]
    float* __restrict__ out)        // [B,T,DOUT]
{
    // Wave 0 (consumer): pure recurrence, 1 ds_read + 1 ds_write per step.
    // Wave 1 (producer): x-projection for chunk c+1, Dense epilogue for chunk c-1.
    __shared__ float xps[2][CHUNK * UU];       // scaled x-projection (+K) per chunk
    __shared__ float hist[2][CHUNK * HISTP];   // u history per chunk
    __shared__ __align__(16) float xs[CHUNK * 12];
    __shared__ __align__(8)  f32x2 wdl2[UU];   // -2*Wd rows

    const int tid = threadIdx.x;
    const int wid = tid >> 6;    // 0 = scan wave, 1 = producer wave
    const int l   = tid & 63;
    const int b   = blockIdx.x;
    const int g   = l >> 4;
    const int r   = l & 15;

    // --- probe DPP row_ror direction (init-only, direction-proof) ---
    int dstep;
    {
        int q = __builtin_amdgcn_mov_dpp(r, 0x121, 0xF, 0xF, false);
        dstep = (q - r) & 15;
    }

    // --- probe permlane swap semantics; pick reduce mode + relabel bits ---
    int mode = 2, alt32 = 0, alt16 = 0;
#if HAS_PL
    {
        float A = pl32_first((l & 32) ? 2.0f : 1.0f);
        int m0 = __all(A == 1.0f), m1 = __all(A == 2.0f);
        if (m0 | m1) {
            float Bv = pl16_first((float)g);
            int n0 = __all(Bv == (float)(g & ~1)), n1 = __all(Bv == (float)(g | 1));
            if (n0 | n1) { mode = 0; alt32 = m1 ? 1 : 0; alt16 = n1 ? 1 : 0; }
        }
    }
#endif
    if (mode != 0) { alt32 = 0; alt16 = 0; }

    // --- Wh fragments, scaled: W2'[k,c] = -2*C*Wh[k,c].
    //     Slot j's unit column chosen so the reduce network lands unit l on lane l.
    f32x2 w2[4][8];
#pragma unroll
    for (int j = 0; j < 4; ++j) {
        const int rho = ((j & 1) ^ alt16) | ((((j >> 1) & 1) ^ alt32) << 1);
        const int cj = r + 16 * rho;
#pragma unroll
        for (int m = 0; m < 8; ++m) {
            const int k0 = 16 * g + ((r + (2 * m) * dstep) & 15);
            const int k1 = 16 * g + ((r + (2 * m + 1) * dstep) & 15);
            f32x2 w;
            w.x = -2.0f * CSCALE * Wh[(size_t)k0 * UU + cj];
            w.y = -2.0f * CSCALE * Wh[(size_t)k1 * UU + cj];
            w2[j][m] = w;
        }
    }

    // --- producer-wave constants: scaled Wx pairs, K_l = C*(b[l] + sum_k Wh[k][l])
    f32x2 wxp[5];
#pragma unroll
    for (int d2 = 0; d2 < 5; ++d2) {
        f32x2 w;
        w.x = CSCALE * Wx[(2 * d2) * UU + l];
        w.y = CSCALE * Wx[(2 * d2 + 1) * UU + l];
        wxp[d2] = w;
    }
    float Kl;
    {
        float s = bias[l];
        for (int k = 0; k < UU; ++k) s += Wh[(size_t)k * UU + l];
        Kl = CSCALE * s;
    }
    // Dense folding: out = (bd + sum_k Wd[k]) + sum_k u_k * (-2*Wd[k])
    f32x2 bdd;
    {
        float s0 = bd[0], s1 = bd[1];
        for (int k = 0; k < UU; ++k) { s0 += Wd[k * DOUT + 0]; s1 += Wd[k * DOUT + 1]; }
        bdd.x = s0; bdd.y = s1;
    }
    if (wid == 0) {
        f32x2 w; w.x = -2.0f * Wd[l * DOUT + 0]; w.y = -2.0f * Wd[l * DOUT + 1];
        wdl2[l] = w;
    }

    const float* xb = x + (size_t)b * TT * DIN;
    float*       ob = out + (size_t)b * TT * DOUT;

    // --- producer helpers -------------------------------------------------
    auto fill_xps = [&](int cn) {
        // stage x rows for chunk cn (coalesced, wave-1 private, same-wave DS order)
        const f32x2* xr = (const f32x2*)(xb + (size_t)(cn * CHUNK + l) * DIN);
        f32x2 v0 = xr[0], v1 = xr[1], v2 = xr[2], v3 = xr[3], v4 = xr[4];
        f32x2* dst = (f32x2*)&xs[l * 12];
        dst[0] = v0; dst[1] = v1; dst[2] = v2; dst[3] = v3; dst[4] = v4;
        float* xp_out = &xps[cn & 1][l];
#pragma unroll 4
        for (int s = 0; s < CHUNK; ++s) {
            const float* p = &xs[s * 12];
            f32x4 xa = ((const f32x4*)p)[0];
            f32x4 xc = ((const f32x4*)p)[1];
            f32x2 xe = ((const f32x2*)p)[4];
            f32x2 acc = {Kl, 0.0f};
            acc = pkfma(__builtin_shufflevector(xa, xa, 0, 1), wxp[0], acc);
            acc = pkfma(__builtin_shufflevector(xa, xa, 2, 3), wxp[1], acc);
            acc = pkfma(__builtin_shufflevector(xc, xc, 0, 1), wxp[2], acc);
            acc = pkfma(__builtin_shufflevector(xc, xc, 2, 3), wxp[3], acc);
            acc = pkfma(xe, wxp[4], acc);
            xp_out[s * UU] = acc.x + acc.y;
        }
    };
    auto dense_chunk = [&](int cd) {
        // lane l emits output for timestep cd*64 + l from hist[cd&1]
        const float* hrow = &hist[cd & 1][l * HISTP];
        f32x2 acc = bdd;
#pragma unroll 8
        for (int k = 0; k < UU; ++k) {
            float u = hrow[k];
            f32x2 uu; uu.x = u; uu.y = u;
            acc = pkfma(uu, wdl2[k], acc);
        }
        float2 o; o.x = acc.x; o.y = acc.y;
        *(float2*)(ob + (size_t)(cd * CHUNK + l) * DOUT) = o;
    };

    // prologue: producer fills chunk 0's x-projection
    if (wid == 1) fill_xps(0);
    __syncthreads();

    auto scan_chunk = [&](auto MC, int c, float u) {
        constexpr int MODE = decltype(MC)::value;
        const float* xpsrc = &xps[c & 1][l];
        float* hdst = &hist[c & 1][l];
#pragma unroll 8
        for (int s = 0; s < CHUNK; ++s) {
            float xpv = xpsrc[s * UU];          // independent of u -> hoistable
            // broadcast u within each 16-lane row, direct to pk pairs
            f32x2 hp[8];
            hp[0].x = u;
            ror_fill<1>(__float_as_int(u), hp);
            // dot with -2C*Wh
            f32x2 a0 = {0.f, 0.f}, a1 = {0.f, 0.f}, a2 = {0.f, 0.f}, a3 = {0.f, 0.f};
#pragma unroll
            for (int m = 0; m < 8; ++m) {
                a0 = pkfma(hp[m], w2[0][m], a0);
                a1 = pkfma(hp[m], w2[1][m], a1);
                a2 = pkfma(hp[m], w2[2][m], a2);
                a3 = pkfma(hp[m], w2[3][m], a3);
            }
            float zr = reduce4<MODE>(a0.x + a0.y, a1.x + a1.y,
                                     a2.x + a2.y, a3.x + a3.y, l);
            float zp = zr + xpv;                // = C*z
#if __has_builtin(__builtin_amdgcn_exp2f)
            float e = __builtin_amdgcn_exp2f(zp);
#else
            float e = exp2f(zp);
#endif
            u = __builtin_amdgcn_rcpf(e + 1.0f);  // u = 1/(e^{2z}+1); h = 1-2u
            hdst[s * HISTP] = u;
        }
        return u;
    };

    float u = 0.5f;  // h_0 = 0
    for (int c = 0; c < NCHUNK; ++c) {
        if (wid == 0) {
            if (mode == 0) u = scan_chunk(IC<0>{}, c, u);
            else           u = scan_chunk(IC<2>{}, c, u);
        } else {
            if (c + 1 < NCHUNK) fill_xps(c + 1);
            if (c > 0)          dense_chunk(c - 1);
        }
        __syncthreads();
    }
    if (wid == 1) dense_chunk(NCHUNK - 1);
}

extern "C" void kernel_launch(void* const* d_in, const int* in_sizes, int n_in,
                              void* d_out, int out_size, void* d_ws, size_t ws_size,
                              hipStream_t stream) {
    const float* x    = (const float*)d_in[0];
    const float* Wx   = (const float*)d_in[1];
    const float* Wh   = (const float*)d_in[2];
    const float* bias = (const float*)d_in[3];
    const float* Wd   = (const float*)d_in[4];
    const float* bd   = (const float*)d_in[5];
    float* out = (float*)d_out;

    rnn_scan_kernel<<<BB, 128, 0, stream>>>(x, Wx, Wh, bias, Wd, bd, out);
}